// Round 11
// baseline (893.187 us; speedup 1.0000x reference)
//
#include <hip/hip_runtime.h>
#include <hip/hip_bf16.h>
#include <math.h>
#include <limits.h>

#define BQ   1024
#define CAP  100000
#define KDIM 2048
#define CDIM 384
#define TOPK 5
#define NKT  32             // K-tiles of 64 i8
#define NT2  391            // ceil(100000/256) col tiles (256 wide)
#define NC2  (NT2*TOPK)     // 1955 candidates/row
#define RSC  16             // rescore set size
// fallback (round-2 proven) params
#define MT   8
#define NT   782
#define NCAND (NT*TOPK)
#define KPAD 56
#define SIMPAD 129

// i8 path ws layout (bytes)
#define WSI_B    0UL            // 391 tiles * 524288 = 204,996,608
#define WSI_A    205000704UL    // 8 tiles * 262144   = 2,097,152
#define WSI_CV   207097856UL    // 1024*1955*4 = 8,007,680
#define WSI_CC   215105536UL    // 1024*1955*4
#define WSI_NEED 223113216UL

typedef int    int4v  __attribute__((ext_vector_type(4)));
typedef float  f32x4  __attribute__((ext_vector_type(4)));
typedef __bf16 bf16x8 __attribute__((ext_vector_type(8)));

__device__ __forceinline__ unsigned short f2bf(float f) {
  unsigned int u = __float_as_uint(f);
  u += 0x7FFF + ((u >> 16) & 1);
  return (unsigned short)(u >> 16);
}

__device__ __forceinline__ void gll16(const unsigned char* src, unsigned char* dst) {
  __builtin_amdgcn_global_load_lds(
      (const __attribute__((address_space(1))) unsigned int*)src,
      (__attribute__((address_space(3))) unsigned int*)dst, 16, 0, 0);
}

__device__ __forceinline__ unsigned int q8pack(float x, float y, float z, float w) {
  #define Q8(v) ((unsigned int)(int)((v) * 127.f + 0.5f))
  return Q8(x) | (Q8(y) << 8) | (Q8(z) << 16) | (Q8(w) << 24);
  #undef Q8
}

// ---------------- K0a: fp32 -> i8 into 128-row-tiled + chunk-XOR'd layout (A) ----------
// Per 128-row tile (262144 B): [kt 0..31][row 0..127][stored-chunk 0..3][16 B].
// stored chunk sc holds logical chunk lc = sc ^ ((row>>1)&3)  (XOR involution).
__global__ __launch_bounds__(256) void k_cvt128(const float* __restrict__ src,
                                                unsigned char* __restrict__ dst,
                                                int nchunks, int nrows) {
  int stride = gridDim.x * 256;
  for (int g = blockIdx.x * 256 + threadIdx.x; g < nchunks; g += stride) {
    int tile = g >> 14;
    int rem  = g & 16383;
    int kt   = rem >> 9;
    int loc  = rem & 511;
    int row  = loc >> 2;
    int sc   = loc & 3;
    int lc   = sc ^ ((row >> 1) & 3);
    int srcRow = tile * 128 + row;
    unsigned int w0 = 0, w1 = 0, w2 = 0, w3 = 0;
    if (srcRow < nrows) {
      const float* sp = src + (size_t)srcRow * KDIM + kt * 64 + lc * 16;
      float4 a = *reinterpret_cast<const float4*>(sp);
      float4 b = *reinterpret_cast<const float4*>(sp + 4);
      float4 c = *reinterpret_cast<const float4*>(sp + 8);
      float4 d = *reinterpret_cast<const float4*>(sp + 12);
      w0 = q8pack(a.x, a.y, a.z, a.w);
      w1 = q8pack(b.x, b.y, b.z, b.w);
      w2 = q8pack(c.x, c.y, c.z, c.w);
      w3 = q8pack(d.x, d.y, d.z, d.w);
    }
    *reinterpret_cast<uint4*>(dst + (size_t)g * 16) = make_uint4(w0, w1, w2, w3);
  }
}

// ---------------- K0b: fp32 -> i8 into 256-row-tiled + chunk-XOR'd layout (B) ----------
// Per 256-row tile (524288 B): [kt 0..31][row 0..255][stored-chunk 0..3][16 B].
__global__ __launch_bounds__(256) void k_cvt256(const float* __restrict__ src,
                                                unsigned char* __restrict__ dst,
                                                int nchunks, int nrows) {
  int stride = gridDim.x * 256;
  for (int g = blockIdx.x * 256 + threadIdx.x; g < nchunks; g += stride) {
    int tile = g >> 15;
    int rem  = g & 32767;
    int kt   = rem >> 10;
    int loc  = rem & 1023;
    int row  = loc >> 2;
    int sc   = loc & 3;
    int lc   = sc ^ ((row >> 1) & 3);
    int srcRow = tile * 256 + row;
    unsigned int w0 = 0, w1 = 0, w2 = 0, w3 = 0;
    if (srcRow < nrows) {
      const float* sp = src + (size_t)srcRow * KDIM + kt * 64 + lc * 16;
      float4 a = *reinterpret_cast<const float4*>(sp);
      float4 b = *reinterpret_cast<const float4*>(sp + 4);
      float4 c = *reinterpret_cast<const float4*>(sp + 8);
      float4 d = *reinterpret_cast<const float4*>(sp + 12);
      w0 = q8pack(a.x, a.y, a.z, a.w);
      w1 = q8pack(b.x, b.y, b.z, b.w);
      w2 = q8pack(c.x, c.y, c.z, c.w);
      w3 = q8pack(d.x, d.y, d.z, d.w);
    }
    *reinterpret_cast<uint4*>(dst + (size_t)g * 16) = make_uint4(w0, w1, w2, w3);
  }
}

// ------- K1: i8 GEMM, 128x256 tile, 8 waves, BK=64, 2-buffer dbuf (round-6 schedule) -------
__global__ __launch_bounds__(512) void k_gemm_w(
    const unsigned char* __restrict__ At, const unsigned char* __restrict__ Bt,
    const int* __restrict__ valid,
    int* __restrict__ cand_v, int* __restrict__ cand_c)
{
  // dbuf: buf c at c*24576 {A 8K | B 16K}; epilogue sim [128][33] i32 aliases smem
  __shared__ __align__(16) unsigned char smem[49152];
  __shared__ int s_valid[256];
  int* sim = (int*)smem;

  const int bid = blockIdx.x;
  const int g = bid >> 6, sub = bid & 63;
  const int rt = sub >> 3;              // 0..7 row tiles (128 rows each)
  const int ct = g * 8 + (sub & 7);     // bid%8 == ct%8 -> B-tile sharers on one XCD
  if (ct >= NT2) return;

  const int tid = threadIdx.x;
  const int lane = tid & 63;
  const int w    = tid >> 6;            // 0..7
  const int wm = w >> 2, wn = w & 3;    // 2M x 4N waves, each owns 64x64
  const int lrow = lane & 15;
  const int swc = (((lane >> 4) ^ ((lrow >> 1) & 3)) << 4);

  const int arow0 = rt * 128, bcol0 = ct * 256;
  if (tid < 256) s_valid[tid] = (bcol0 + tid < CAP) ? valid[bcol0 + tid] : 0;

  int4v acc[4][4];
  const int4v z4 = {0, 0, 0, 0};
  #pragma unroll
  for (int m = 0; m < 4; ++m)
    #pragma unroll
    for (int n = 0; n < 4; ++n) acc[m][n] = z4;

  const unsigned char* gAt = At + (size_t)rt * 262144;   // 128-row tile, kt stride 8192
  const unsigned char* gBt = Bt + (size_t)ct * 524288;   // 256-row tile, kt stride 16384

  // stage K-tile kt into buffer b: A 8KB (1 gll/thr) + B 16KB (2 gll/thr)
  auto STG = [&](int b, int kt) {
    gll16(gAt + kt * 8192 + tid * 16, smem + b * 24576 + w * 1024);
    #pragma unroll
    for (int j = 0; j < 2; ++j)
      gll16(gBt + kt * 16384 + j * 8192 + tid * 16,
            smem + b * 24576 + 8192 + j * 8192 + w * 1024);
  };

  STG(0, 0);
  __syncthreads();

  for (int kt = 0; kt < NKT; ++kt) {
    const int cur = kt & 1;
    if (kt + 1 < NKT) STG(cur ^ 1, kt + 1);   // issue next tile first; hides under compute

    const unsigned char* la = smem + cur * 24576;
    const unsigned char* lb = la + 8192;
    int4v af[4], bfr[4];
    #pragma unroll
    for (int m = 0; m < 4; ++m)
      af[m] = *reinterpret_cast<const int4v*>(la + (wm*64 + m*16 + lrow) * 64 + swc);
    #pragma unroll
    for (int n = 0; n < 4; ++n)
      bfr[n] = *reinterpret_cast<const int4v*>(lb + (wn*64 + n*16 + lrow) * 64 + swc);

    #pragma unroll
    for (int m = 0; m < 4; ++m)
      #pragma unroll
      for (int n = 0; n < 4; ++n)
        acc[m][n] = __builtin_amdgcn_mfma_i32_16x16x64_i8(af[m], bfr[n], acc[m][n], 0, 0, 0);

    __syncthreads();   // single drain per iter
  }

  // epilogue: 8 chunks of 32 cols via [128][33] i32 slab; running top-5 in regs
  int ts[TOPK]; int tc[TOPK];
  #pragma unroll
  for (int i = 0; i < TOPK; ++i) { ts[i] = INT_MIN; tc[i] = 0x7FFFFFFF; }

  for (int c = 0; c < 8; ++c) {
    __syncthreads();
    if (wn == (c >> 1)) {
      #pragma unroll
      for (int m = 0; m < 4; ++m) {
        #pragma unroll
        for (int nn = 0; nn < 2; ++nn) {
          int n = (c & 1) * 2 + nn;
          int rowb = wm*64 + m*16 + (lane >> 4) * 4;
          int lcol = nn*16 + lrow;
          #pragma unroll
          for (int r = 0; r < 4; ++r)
            sim[(rowb + r) * 33 + lcol] = acc[m][n][r];
        }
      }
    }
    __syncthreads();
    if (tid < 128) {
      #pragma unroll 4
      for (int j = 0; j < 32; ++j) {
        int jj = c * 32 + j;
        int v = sim[tid * 33 + j];
        if (s_valid[jj] && v > ts[TOPK-1]) {
          int col = bcol0 + jj;
          int p = TOPK - 1;
          while (p > 0 && v > ts[p-1]) { ts[p] = ts[p-1]; tc[p] = tc[p-1]; --p; }
          ts[p] = v; tc[p] = col;
        }
      }
    }
  }

  if (tid < 128) {
    size_t base = ((size_t)(arow0 + tid) * NT2 + ct) * TOPK;
    #pragma unroll
    for (int i = 0; i < TOPK; ++i) { cand_v[base + i] = ts[i]; cand_c[base + i] = tc[i]; }
  }
}

// ---------------- K2: merge 1955 int candidates -> top-16 -> exact fp64 rescore -------------
__global__ __launch_bounds__(256) void k_select16(
    const float* __restrict__ Aq, const float* __restrict__ Bb,
    const float* __restrict__ content,
    const int* __restrict__ cand_v, const int* __restrict__ cand_c,
    float* __restrict__ out)
{
  __shared__ int    s_s[NC2];
  __shared__ int    s_c[NC2];
  __shared__ float  s_q[KDIM];
  __shared__ int    w_v[4], w_c[4], w_p[4];
  __shared__ int    sel_c[RSC];
  __shared__ double sel_v[RSC];
  __shared__ int    o_col[TOPK], o_ok[TOPK];

  const int tid = threadIdx.x;
  const int b   = blockIdx.x;
  const int wid = tid >> 6, lane = tid & 63;

  size_t cbase = (size_t)b * NC2;
  for (int i = tid; i < NC2; i += 256) { s_s[i] = cand_v[cbase + i]; s_c[i] = cand_c[cbase + i]; }
  for (int i = tid; i < KDIM; i += 256) s_q[i] = Aq[(size_t)b * KDIM + i];
  if (tid < TOPK) { o_ok[tid] = 0; o_col[tid] = 0; }
  __syncthreads();

  for (int k = 0; k < RSC; ++k) {
    int best = INT_MIN, bc = 0x7FFFFFFF, bp = 0;
    for (int i = tid; i < NC2; i += 256) {
      int v = s_s[i], cc = s_c[i];
      if (v > best || (v == best && cc < bc)) { best = v; bc = cc; bp = i; }
    }
    #pragma unroll
    for (int off = 32; off > 0; off >>= 1) {
      int v2 = __shfl_xor(best, off); int c2 = __shfl_xor(bc, off); int p2 = __shfl_xor(bp, off);
      if (v2 > best || (v2 == best && c2 < bc)) { best = v2; bc = c2; bp = p2; }
    }
    if (lane == 0) { w_v[wid] = best; w_c[wid] = bc; w_p[wid] = bp; }
    __syncthreads();
    if (tid == 0) {
      int bv = w_v[0], bcc = w_c[0], bpp = w_p[0];
      #pragma unroll
      for (int ww = 1; ww < 4; ++ww)
        if (w_v[ww] > bv || (w_v[ww] == bv && w_c[ww] < bcc)) { bv = w_v[ww]; bcc = w_c[ww]; bpp = w_p[ww]; }
      sel_c[k] = bcc; s_s[bpp] = INT_MIN;
    }
    __syncthreads();
  }

  for (int q = 0; q < 4; ++q) {
    int i  = wid * 4 + q;
    int cc = sel_c[i];
    bool ok = (cc >= 0 && cc < CAP);
    double a = 0.0;
    if (ok) {
      const float* brow = &Bb[(size_t)cc * KDIM];
      #pragma unroll 4
      for (int j = 0; j < KDIM / 64; ++j) {
        int kk = j * 64 + lane;
        a += (double)s_q[kk] * (double)brow[kk];
      }
    }
    #pragma unroll
    for (int off = 32; off > 0; off >>= 1) a += __shfl_down(a, off);
    if (lane == 0) sel_v[i] = ok ? a : -INFINITY;
  }
  __syncthreads();

  if (tid < RSC) {
    double my = sel_v[tid]; int mc = sel_c[tid];
    int rank = 0;
    for (int j = 0; j < RSC; ++j) {
      double ov = sel_v[j]; int oc = sel_c[j];
      if (ov > my || (ov == my && (oc < mc || (oc == mc && j < tid)))) ++rank;
    }
    if (rank < TOPK) {
      double simv = my * (1.0 / 40.0);
      int pass = (my != -INFINITY) && (simv >= 0.3);
      out[(size_t)BQ * TOPK * CDIM + (size_t)b * TOPK + rank] = pass ? (float)simv : 0.0f;
      o_col[rank] = mc; o_ok[rank] = pass;
    }
  }
  __syncthreads();

  for (int idx = tid; idx < TOPK * CDIM; idx += 256) {
    int slot = idx / CDIM;
    int d    = idx - slot * CDIM;
    float v  = 0.f;
    if (o_ok[slot]) v = content[(size_t)o_col[slot] * CDIM + d];
    out[(size_t)b * TOPK * CDIM + idx] = v;
  }
}

// ---------------- fallback: round-2 proven fp32 path ----------------
__global__ __launch_bounds__(256) void k_gemm_cand(
    const float* __restrict__ Aq, const float* __restrict__ Bb,
    const int* __restrict__ valid,
    float* __restrict__ cand_s, int* __restrict__ cand_c)
{
  __shared__ __align__(16) unsigned char smem[128*SIMPAD*4];
  __shared__ int s_valid[128];
  unsigned short* lds_a = (unsigned short*)smem;
  unsigned short* lds_b = lds_a + 128*KPAD;
  float* sim = (float*)smem;

  const int tid = threadIdx.x;
  const int bid = blockIdx.x;
  const int rt = bid & 7;
  const int ct = bid >> 3;
  const int lane = tid & 63;
  const int wid  = tid >> 6;
  const int wr = wid >> 1;
  const int wc = wid & 1;
  const int lrow = lane & 15;
  const int lko  = (lane >> 4) * 8;

  const int arow0 = rt * 128;
  const int brow0 = ct * 128;

  if (tid < 128) {
    int col = brow0 + tid;
    s_valid[tid] = (col < CAP) ? valid[col] : 0;
  }

  f32x4 acc[4][4];
  const f32x4 zero4 = {0.f, 0.f, 0.f, 0.f};
  #pragma unroll
  for (int m = 0; m < 4; ++m)
    #pragma unroll
    for (int n = 0; n < 4; ++n) acc[m][n] = zero4;

  for (int k0 = 0; k0 < KDIM; k0 += 32) {
    #pragma unroll
    for (int it = 0; it < 4; ++it) {
      int idx = it * 256 + tid;
      int row = idx >> 3;
      int kq  = (idx & 7) * 4;
      float4 av = *reinterpret_cast<const float4*>(&Aq[(size_t)(arow0 + row) * KDIM + k0 + kq]);
      ushort4 pa = make_ushort4(f2bf(av.x), f2bf(av.y), f2bf(av.z), f2bf(av.w));
      *reinterpret_cast<ushort4*>(&lds_a[row * KPAD + kq]) = pa;
      int br = brow0 + row;
      float4 bv = make_float4(0.f, 0.f, 0.f, 0.f);
      if (br < CAP) bv = *reinterpret_cast<const float4*>(&Bb[(size_t)br * KDIM + k0 + kq]);
      ushort4 pb = make_ushort4(f2bf(bv.x), f2bf(bv.y), f2bf(bv.z), f2bf(bv.w));
      *reinterpret_cast<ushort4*>(&lds_b[row * KPAD + kq]) = pb;
    }
    __syncthreads();

    bf16x8 af2[4], bf2[4];
    #pragma unroll
    for (int m = 0; m < 4; ++m)
      af2[m] = *reinterpret_cast<const bf16x8*>(&lds_a[(wr*64 + m*16 + lrow) * KPAD + lko]);
    #pragma unroll
    for (int n = 0; n < 4; ++n)
      bf2[n] = *reinterpret_cast<const bf16x8*>(&lds_b[(wc*64 + n*16 + lrow) * KPAD + lko]);

    #pragma unroll
    for (int m = 0; m < 4; ++m)
      #pragma unroll
      for (int n = 0; n < 4; ++n)
        acc[m][n] = __builtin_amdgcn_mfma_f32_16x16x32_bf16(af2[m], bf2[n], acc[m][n], 0, 0, 0);
    __syncthreads();
  }

  #pragma unroll
  for (int m = 0; m < 4; ++m) {
    #pragma unroll
    for (int n = 0; n < 4; ++n) {
      int col  = wc*64 + n*16 + (lane & 15);
      int rowb = wr*64 + m*16 + (lane >> 4) * 4;
      #pragma unroll
      for (int r = 0; r < 4; ++r)
        sim[(rowb + r) * SIMPAD + col] = acc[m][n][r];
    }
  }
  __syncthreads();

  if (tid < 128) {
    float s[TOPK]; int c[TOPK];
    #pragma unroll
    for (int i = 0; i < TOPK; ++i) { s[i] = -INFINITY; c[i] = 0x7FFFFFFF; }
    for (int j = 0; j < 128; ++j) {
      int col = brow0 + j;
      if (col >= CAP) break;
      if (!s_valid[j]) continue;
      float v = sim[tid * SIMPAD + j];
      if (v > s[TOPK-1]) {
        int p = TOPK - 1;
        while (p > 0 && v > s[p-1]) { s[p] = s[p-1]; c[p] = c[p-1]; --p; }
        s[p] = v; c[p] = col;
      }
    }
    size_t base = ((size_t)(arow0 + tid) * NT + ct) * TOPK;
    #pragma unroll
    for (int i = 0; i < TOPK; ++i) { cand_s[base + i] = s[i]; cand_c[base + i] = c[i]; }
  }
}

__global__ __launch_bounds__(256) void k_select(
    const float* __restrict__ Aq, const float* __restrict__ Bb,
    const float* __restrict__ content,
    const float* __restrict__ cand_s, const int* __restrict__ cand_c,
    float* __restrict__ out)
{
  __shared__ float  s_s[NCAND];
  __shared__ int    s_c[NCAND];
  __shared__ float  s_q[KDIM];
  __shared__ float  r_s[256];
  __shared__ int    r_c[256];
  __shared__ int    r_p[256];
  __shared__ int    sel_c[32];
  __shared__ double sel_v[32];
  __shared__ int    o_col[TOPK];
  __shared__ int    o_ok[TOPK];

  const int tid = threadIdx.x;
  const int b   = blockIdx.x;

  size_t cbase = (size_t)b * NCAND;
  for (int i = tid; i < NCAND; i += 256) { s_s[i] = cand_s[cbase + i]; s_c[i] = cand_c[cbase + i]; }
  for (int i = tid; i < KDIM; i += 256) s_q[i] = Aq[(size_t)b * KDIM + i];
  if (tid < TOPK) { o_ok[tid] = 0; o_col[tid] = 0; }
  __syncthreads();

  for (int k = 0; k < 32; ++k) {
    float best = -INFINITY; int bc = 0x7FFFFFFF; int bp = 0;
    for (int i = tid; i < NCAND; i += 256) {
      float v = s_s[i]; int cc = s_c[i];
      if (v > best || (v == best && cc < bc)) { best = v; bc = cc; bp = i; }
    }
    r_s[tid] = best; r_c[tid] = bc; r_p[tid] = bp;
    __syncthreads();
    for (int off = 128; off > 0; off >>= 1) {
      if (tid < off) {
        float v = r_s[tid + off]; int cc = r_c[tid + off];
        if (v > r_s[tid] || (v == r_s[tid] && cc < r_c[tid])) {
          r_s[tid] = v; r_c[tid] = cc; r_p[tid] = r_p[tid + off];
        }
      }
      __syncthreads();
    }
    if (tid == 0) { sel_c[k] = r_c[0]; s_s[r_p[0]] = -INFINITY; }
    __syncthreads();
  }

  const int wid = tid >> 6, lane = tid & 63;
  for (int q = 0; q < 8; ++q) {
    int i  = wid * 8 + q;
    int cc = sel_c[i];
    bool ok = (cc >= 0 && cc < CAP);
    double a = 0.0;
    if (ok) {
      const float* brow = &Bb[(size_t)cc * KDIM];
      #pragma unroll 4
      for (int j = 0; j < KDIM / 64; ++j) {
        int kk = j * 64 + lane;
        a += (double)s_q[kk] * (double)brow[kk];
      }
    }
    #pragma unroll
    for (int off = 32; off > 0; off >>= 1) a += __shfl_down(a, off);
    if (lane == 0) sel_v[i] = ok ? a : -INFINITY;
  }
  __syncthreads();

  if (tid < 32) {
    double my = sel_v[tid]; int mc = sel_c[tid];
    int rank = 0;
    for (int j = 0; j < 32; ++j) {
      double ov = sel_v[j]; int oc = sel_c[j];
      if (ov > my || (ov == my && (oc < mc || (oc == mc && j < tid)))) ++rank;
    }
    if (rank < TOPK) {
      double simv = my * (1.0 / 40.0);
      int pass = (my != -INFINITY) && (simv >= 0.3);
      out[(size_t)BQ * TOPK * CDIM + (size_t)b * TOPK + rank] = pass ? (float)simv : 0.0f;
      o_col[rank] = mc; o_ok[rank] = pass;
    }
  }
  __syncthreads();

  for (int idx = tid; idx < TOPK * CDIM; idx += 256) {
    int slot = idx / CDIM;
    int d    = idx - slot * CDIM;
    float v  = 0.f;
    if (o_ok[slot]) v = content[(size_t)o_col[slot] * CDIM + d];
    out[(size_t)b * TOPK * CDIM + idx] = v;
  }
}

extern "C" void kernel_launch(void* const* d_in, const int* in_sizes, int n_in,
                              void* d_out, int out_size, void* d_ws, size_t ws_size,
                              hipStream_t stream) {
  const float* q        = (const float*)d_in[0];
  const float* bank     = (const float*)d_in[1];
  const float* content  = (const float*)d_in[2];
  const int*   valid    = (const int*)d_in[3];
  float* out = (float*)d_out;

  if (ws_size >= WSI_NEED) {
    unsigned char* Bt = (unsigned char*)d_ws + WSI_B;
    unsigned char* At = (unsigned char*)d_ws + WSI_A;
    int* cand_v = (int*)((char*)d_ws + WSI_CV);
    int* cand_c = (int*)((char*)d_ws + WSI_CC);

    k_cvt256<<<dim3(4096), dim3(256), 0, stream>>>(bank, Bt, NT2 * 32768, CAP);
    k_cvt128<<<dim3(512),  dim3(256), 0, stream>>>(q,    At, MT * 16384, BQ);
    k_gemm_w<<<dim3(49 * 64), dim3(512), 0, stream>>>(At, Bt, valid, cand_v, cand_c);
    k_select16<<<dim3(BQ), dim3(256), 0, stream>>>(q, bank, content, cand_v, cand_c, out);
  } else {
    float* cand_s = (float*)d_ws;
    int*   cand_c = (int*)((char*)d_ws + (size_t)BQ * NCAND * 4);
    k_gemm_cand<<<dim3(MT * NT), dim3(256), 0, stream>>>(q, bank, valid, cand_s, cand_c);
    k_select<<<dim3(BQ), dim3(256), 0, stream>>>(q, bank, content, cand_s, cand_c, out);
  }
}

// Round 12
// 699.908 us; speedup vs baseline: 1.2761x; 1.2761x over previous
//
#include <hip/hip_runtime.h>
#include <hip/hip_bf16.h>
#include <math.h>
#include <limits.h>

#define BQ   1024
#define CAP  100000
#define KDIM 2048
#define CDIM 384
#define TOPK 5
#define MT   8
#define NT   782            // ceil(100000/128)
#define NCAND (NT*TOPK)     // 3910
#define NKT  32             // K-tiles of 64 i8
#define RSC  16             // rescore set size
// fallback (round-2 proven) params
#define KPAD 56
#define SIMPAD 129

// i8 path ws layout (bytes)
#define WSI_B    0UL            // 782 tiles * 262144 = 205,000,704
#define WSI_A    205000704UL    // 8 tiles * 262144   = 2,097,152
#define WSI_CV   207097856UL    // 1024*3910*4
#define WSI_CC   223113216UL    // 1024*3910*4
#define WSI_NEED 239128576UL

typedef int    int4v  __attribute__((ext_vector_type(4)));
typedef float  f32x4  __attribute__((ext_vector_type(4)));
typedef __bf16 bf16x8 __attribute__((ext_vector_type(8)));

__device__ __forceinline__ unsigned short f2bf(float f) {
  unsigned int u = __float_as_uint(f);
  u += 0x7FFF + ((u >> 16) & 1);
  return (unsigned short)(u >> 16);
}

// ---------------- K0: fp32 -> i8 (x127) into tiled+chunk-XOR'd layout ----------------
// Per 128-row tile (262144 B): [kt 0..31][row 0..127][stored-chunk 0..3][16 B].
// stored chunk sc holds logical chunk lc = sc ^ ((row>>1)&3)  (XOR involution).
__global__ __launch_bounds__(256) void k_cvt_i8(const float* __restrict__ src,
                                                unsigned char* __restrict__ dst,
                                                int nchunks, int nrows) {
  int stride = gridDim.x * 256;
  for (int g = blockIdx.x * 256 + threadIdx.x; g < nchunks; g += stride) {
    int tile = g >> 14;          // 16384 16B-chunks per tile
    int rem  = g & 16383;
    int kt   = rem >> 9;         // 512 chunks per K-tile (128 rows x 4)
    int loc  = rem & 511;
    int row  = loc >> 2;
    int sc   = loc & 3;
    int lc   = sc ^ ((row >> 1) & 3);
    int srcRow = tile * 128 + row;
    unsigned int w0 = 0, w1 = 0, w2 = 0, w3 = 0;
    if (srcRow < nrows) {
      const float* sp = src + (size_t)srcRow * KDIM + kt * 64 + lc * 16;
      float4 a = *reinterpret_cast<const float4*>(sp);
      float4 b = *reinterpret_cast<const float4*>(sp + 4);
      float4 c = *reinterpret_cast<const float4*>(sp + 8);
      float4 d = *reinterpret_cast<const float4*>(sp + 12);
      #define Q8(x) ((unsigned int)(int)((x) * 127.f + 0.5f))
      w0 = Q8(a.x) | (Q8(a.y) << 8) | (Q8(a.z) << 16) | (Q8(a.w) << 24);
      w1 = Q8(b.x) | (Q8(b.y) << 8) | (Q8(b.z) << 16) | (Q8(b.w) << 24);
      w2 = Q8(c.x) | (Q8(c.y) << 8) | (Q8(c.z) << 16) | (Q8(c.w) << 24);
      w3 = Q8(d.x) | (Q8(d.y) << 8) | (Q8(d.z) << 16) | (Q8(d.w) << 24);
      #undef Q8
    }
    *reinterpret_cast<uint4*>(dst + (size_t)g * 16) = make_uint4(w0, w1, w2, w3);
  }
}

// ---------------- K1: i8 MFMA GEMM, 2-phase double-buffered (round-6 proven) ----------
__global__ __launch_bounds__(256) void k_gemm_i8(
    const unsigned char* __restrict__ At, const unsigned char* __restrict__ Bt,
    const int* __restrict__ valid,
    int* __restrict__ cand_v, int* __restrict__ cand_c)
{
  // dbuf: buf c at c*16384 {A 8KB | B 8KB}; epilogue sim [128][33] i32 aliases smem
  __shared__ __align__(16) unsigned char smem[32768];
  __shared__ int s_valid[128];
  int* sim = (int*)smem;

  const int bid = blockIdx.x;
  const int g = bid >> 6, sub = bid & 63;
  const int rt = sub >> 3;
  const int ct = g * 8 + (sub & 7);     // bid%8 == ct%8 -> B-tile sharers on one XCD
  if (ct >= NT) return;

  const int tid = threadIdx.x;
  const int lane = tid & 63;
  const int w    = tid >> 6;
  const int wr = w >> 1, wc = w & 1;
  const int lrow = lane & 15;
  // stored-chunk byte offset for this lane's K-chunk (XOR involution, lane-only)
  const int swc = (((lane >> 4) ^ ((lrow >> 1) & 3)) << 4);

  const int arow0 = rt * 128, brow0 = ct * 128;
  if (tid < 128) s_valid[tid] = (brow0 + tid < CAP) ? valid[brow0 + tid] : 0;

  int4v acc[4][4];
  const int4v z4 = {0, 0, 0, 0};
  #pragma unroll
  for (int m = 0; m < 4; ++m)
    #pragma unroll
    for (int n = 0; n < 4; ++n) acc[m][n] = z4;

  const unsigned char* gAt = At + (size_t)rt * 262144;
  const unsigned char* gBt = Bt + (size_t)ct * 262144;

  // stage K-tile kt into buffer b (wave-uniform LDS base; lane lands at +lane*16)
  auto STG = [&](int b, int kt) {
    #pragma unroll
    for (int j = 0; j < 2; ++j) {
      const unsigned char* sA = gAt + kt * 8192 + j * 4096 + tid * 16;
      unsigned char* dA = smem + b * 16384 + j * 4096 + w * 1024;
      __builtin_amdgcn_global_load_lds(
          (const __attribute__((address_space(1))) unsigned int*)sA,
          (__attribute__((address_space(3))) unsigned int*)dA, 16, 0, 0);
      const unsigned char* sB = gBt + kt * 8192 + j * 4096 + tid * 16;
      unsigned char* dB = smem + b * 16384 + 8192 + j * 4096 + w * 1024;
      __builtin_amdgcn_global_load_lds(
          (const __attribute__((address_space(1))) unsigned int*)sB,
          (__attribute__((address_space(3))) unsigned int*)dB, 16, 0, 0);
    }
  };

  STG(0, 0);
  __syncthreads();   // vmcnt(0): tile 0 resident

  for (int kt = 0; kt < NKT; ++kt) {
    const int cur = kt & 1;
    // issue next-tile staging FIRST -> HBM latency hides under ds_read + MFMA
    if (kt + 1 < NKT) STG(cur ^ 1, kt + 1);

    const unsigned char* la = smem + cur * 16384;
    const unsigned char* lb = la + 8192;
    int4v af[4], bfr[4];
    #pragma unroll
    for (int m = 0; m < 4; ++m)
      af[m] = *reinterpret_cast<const int4v*>(la + (wr*64 + m*16 + lrow) * 64 + swc);
    #pragma unroll
    for (int n = 0; n < 4; ++n)
      bfr[n] = *reinterpret_cast<const int4v*>(lb + (wc*64 + n*16 + lrow) * 64 + swc);

    #pragma unroll
    for (int m = 0; m < 4; ++m)
      #pragma unroll
      for (int n = 0; n < 4; ++n)
        acc[m][n] = __builtin_amdgcn_mfma_i32_16x16x64_i8(af[m], bfr[n], acc[m][n], 0, 0, 0);

    __syncthreads();   // single drain per iter: next tile resident, frag reads done
  }

  // epilogue: 4 chunks of 32 cols via [128][33] i32 slab; running top-5 in regs
  int ts[TOPK]; int tc[TOPK];
  #pragma unroll
  for (int i = 0; i < TOPK; ++i) { ts[i] = INT_MIN; tc[i] = 0x7FFFFFFF; }

  for (int c = 0; c < 4; ++c) {
    __syncthreads();
    if (wc == (c >> 1)) {
      #pragma unroll
      for (int m = 0; m < 4; ++m) {
        #pragma unroll
        for (int nn = 0; nn < 2; ++nn) {
          int n = (c & 1) * 2 + nn;
          int rowb = wr*64 + m*16 + (lane >> 4) * 4;
          int lcol = nn*16 + lrow;
          #pragma unroll
          for (int r = 0; r < 4; ++r)
            sim[(rowb + r) * 33 + lcol] = acc[m][n][r];
        }
      }
    }
    __syncthreads();
    if (tid < 128) {
      #pragma unroll 4
      for (int j = 0; j < 32; ++j) {
        int jj = c * 32 + j;
        int v = sim[tid * 33 + j];
        if (s_valid[jj] && v > ts[TOPK-1]) {
          int col = brow0 + jj;
          int p = TOPK - 1;
          while (p > 0 && v > ts[p-1]) { ts[p] = ts[p-1]; tc[p] = tc[p-1]; --p; }
          ts[p] = v; tc[p] = col;
        }
      }
    }
  }

  if (tid < 128) {
    size_t base = ((size_t)(arow0 + tid) * NT + ct) * TOPK;
    #pragma unroll
    for (int i = 0; i < TOPK; ++i) { cand_v[base + i] = ts[i]; cand_c[base + i] = tc[i]; }
  }
}

// ---------------- K2: merge int candidates -> top-16 -> exact fp64 rescore -> output --------
__global__ __launch_bounds__(256) void k_select16(
    const float* __restrict__ Aq, const float* __restrict__ Bb,
    const float* __restrict__ content,
    const int* __restrict__ cand_v, const int* __restrict__ cand_c,
    float* __restrict__ out)
{
  __shared__ int    s_s[NCAND];
  __shared__ int    s_c[NCAND];
  __shared__ float  s_q[KDIM];
  __shared__ int    w_v[4], w_c[4], w_p[4];
  __shared__ int    sel_c[RSC];
  __shared__ double sel_v[RSC];
  __shared__ int    o_col[TOPK], o_ok[TOPK];

  const int tid = threadIdx.x;
  const int b   = blockIdx.x;
  const int wid = tid >> 6, lane = tid & 63;

  size_t cbase = (size_t)b * NCAND;
  for (int i = tid; i < NCAND; i += 256) { s_s[i] = cand_v[cbase + i]; s_c[i] = cand_c[cbase + i]; }
  for (int i = tid; i < KDIM; i += 256) s_q[i] = Aq[(size_t)b * KDIM + i];
  if (tid < TOPK) { o_ok[tid] = 0; o_col[tid] = 0; }
  __syncthreads();

  // 16 x argmax over int scores (tie -> lowest col); wave-shuffle + 4-wave merge
  for (int k = 0; k < RSC; ++k) {
    int best = INT_MIN, bc = 0x7FFFFFFF, bp = 0;
    for (int i = tid; i < NCAND; i += 256) {
      int v = s_s[i], cc = s_c[i];
      if (v > best || (v == best && cc < bc)) { best = v; bc = cc; bp = i; }
    }
    #pragma unroll
    for (int off = 32; off > 0; off >>= 1) {
      int v2 = __shfl_xor(best, off); int c2 = __shfl_xor(bc, off); int p2 = __shfl_xor(bp, off);
      if (v2 > best || (v2 == best && c2 < bc)) { best = v2; bc = c2; bp = p2; }
    }
    if (lane == 0) { w_v[wid] = best; w_c[wid] = bc; w_p[wid] = bp; }
    __syncthreads();
    if (tid == 0) {
      int bv = w_v[0], bcc = w_c[0], bpp = w_p[0];
      #pragma unroll
      for (int ww = 1; ww < 4; ++ww)
        if (w_v[ww] > bv || (w_v[ww] == bv && w_c[ww] < bcc)) { bv = w_v[ww]; bcc = w_c[ww]; bpp = w_p[ww]; }
      sel_c[k] = bcc; s_s[bpp] = INT_MIN;
    }
    __syncthreads();
  }

  // exact fp64 rescore: 4 waves x 4 candidates
  for (int q = 0; q < 4; ++q) {
    int i  = wid * 4 + q;
    int cc = sel_c[i];
    bool ok = (cc >= 0 && cc < CAP);
    double a = 0.0;
    if (ok) {
      const float* brow = &Bb[(size_t)cc * KDIM];
      #pragma unroll 4
      for (int j = 0; j < KDIM / 64; ++j) {
        int kk = j * 64 + lane;
        a += (double)s_q[kk] * (double)brow[kk];
      }
    }
    #pragma unroll
    for (int off = 32; off > 0; off >>= 1) a += __shfl_down(a, off);
    if (lane == 0) sel_v[i] = ok ? a : -INFINITY;
  }
  __syncthreads();

  // exact ranking of the 16 (score desc, col asc, pos asc), emit top-5
  if (tid < RSC) {
    double my = sel_v[tid]; int mc = sel_c[tid];
    int rank = 0;
    for (int j = 0; j < RSC; ++j) {
      double ov = sel_v[j]; int oc = sel_c[j];
      if (ov > my || (ov == my && (oc < mc || (oc == mc && j < tid)))) ++rank;
    }
    if (rank < TOPK) {
      double simv = my * (1.0 / 40.0);
      int pass = (my != -INFINITY) && (simv >= 0.3);
      out[(size_t)BQ * TOPK * CDIM + (size_t)b * TOPK + rank] = pass ? (float)simv : 0.0f;
      o_col[rank] = mc; o_ok[rank] = pass;
    }
  }
  __syncthreads();

  for (int idx = tid; idx < TOPK * CDIM; idx += 256) {
    int slot = idx / CDIM;
    int d    = idx - slot * CDIM;
    float v  = 0.f;
    if (o_ok[slot]) v = content[(size_t)o_col[slot] * CDIM + d];
    out[(size_t)b * TOPK * CDIM + idx] = v;
  }
}

// ---------------- fallback: round-2 proven fp32 path ----------------
__global__ __launch_bounds__(256) void k_gemm_cand(
    const float* __restrict__ Aq, const float* __restrict__ Bb,
    const int* __restrict__ valid,
    float* __restrict__ cand_s, int* __restrict__ cand_c)
{
  __shared__ __align__(16) unsigned char smem[128*SIMPAD*4];
  __shared__ int s_valid[128];
  unsigned short* lds_a = (unsigned short*)smem;
  unsigned short* lds_b = lds_a + 128*KPAD;
  float* sim = (float*)smem;

  const int tid = threadIdx.x;
  const int bid = blockIdx.x;
  const int rt = bid & 7;
  const int ct = bid >> 3;
  const int lane = tid & 63;
  const int wid  = tid >> 6;
  const int wr = wid >> 1;
  const int wc = wid & 1;
  const int lrow = lane & 15;
  const int lko  = (lane >> 4) * 8;

  const int arow0 = rt * 128;
  const int brow0 = ct * 128;

  if (tid < 128) {
    int col = brow0 + tid;
    s_valid[tid] = (col < CAP) ? valid[col] : 0;
  }

  f32x4 acc[4][4];
  const f32x4 zero4 = {0.f, 0.f, 0.f, 0.f};
  #pragma unroll
  for (int m = 0; m < 4; ++m)
    #pragma unroll
    for (int n = 0; n < 4; ++n) acc[m][n] = zero4;

  for (int k0 = 0; k0 < KDIM; k0 += 32) {
    #pragma unroll
    for (int it = 0; it < 4; ++it) {
      int idx = it * 256 + tid;
      int row = idx >> 3;
      int kq  = (idx & 7) * 4;
      float4 av = *reinterpret_cast<const float4*>(&Aq[(size_t)(arow0 + row) * KDIM + k0 + kq]);
      ushort4 pa = make_ushort4(f2bf(av.x), f2bf(av.y), f2bf(av.z), f2bf(av.w));
      *reinterpret_cast<ushort4*>(&lds_a[row * KPAD + kq]) = pa;
      int br = brow0 + row;
      float4 bv = make_float4(0.f, 0.f, 0.f, 0.f);
      if (br < CAP) bv = *reinterpret_cast<const float4*>(&Bb[(size_t)br * KDIM + k0 + kq]);
      ushort4 pb = make_ushort4(f2bf(bv.x), f2bf(bv.y), f2bf(bv.z), f2bf(bv.w));
      *reinterpret_cast<ushort4*>(&lds_b[row * KPAD + kq]) = pb;
    }
    __syncthreads();

    bf16x8 af2[4], bf2[4];
    #pragma unroll
    for (int m = 0; m < 4; ++m)
      af2[m] = *reinterpret_cast<const bf16x8*>(&lds_a[(wr*64 + m*16 + lrow) * KPAD + lko]);
    #pragma unroll
    for (int n = 0; n < 4; ++n)
      bf2[n] = *reinterpret_cast<const bf16x8*>(&lds_b[(wc*64 + n*16 + lrow) * KPAD + lko]);

    #pragma unroll
    for (int m = 0; m < 4; ++m)
      #pragma unroll
      for (int n = 0; n < 4; ++n)
        acc[m][n] = __builtin_amdgcn_mfma_f32_16x16x32_bf16(af2[m], bf2[n], acc[m][n], 0, 0, 0);
    __syncthreads();
  }

  #pragma unroll
  for (int m = 0; m < 4; ++m) {
    #pragma unroll
    for (int n = 0; n < 4; ++n) {
      int col  = wc*64 + n*16 + (lane & 15);
      int rowb = wr*64 + m*16 + (lane >> 4) * 4;
      #pragma unroll
      for (int r = 0; r < 4; ++r)
        sim[(rowb + r) * SIMPAD + col] = acc[m][n][r];
    }
  }
  __syncthreads();

  if (tid < 128) {
    float s[TOPK]; int c[TOPK];
    #pragma unroll
    for (int i = 0; i < TOPK; ++i) { s[i] = -INFINITY; c[i] = 0x7FFFFFFF; }
    for (int j = 0; j < 128; ++j) {
      int col = brow0 + j;
      if (col >= CAP) break;
      if (!s_valid[j]) continue;
      float v = sim[tid * SIMPAD + j];
      if (v > s[TOPK-1]) {
        int p = TOPK - 1;
        while (p > 0 && v > s[p-1]) { s[p] = s[p-1]; c[p] = c[p-1]; --p; }
        s[p] = v; c[p] = col;
      }
    }
    size_t base = ((size_t)(arow0 + tid) * NT + ct) * TOPK;
    #pragma unroll
    for (int i = 0; i < TOPK; ++i) { cand_s[base + i] = s[i]; cand_c[base + i] = c[i]; }
  }
}

__global__ __launch_bounds__(256) void k_select(
    const float* __restrict__ Aq, const float* __restrict__ Bb,
    const float* __restrict__ content,
    const float* __restrict__ cand_s, const int* __restrict__ cand_c,
    float* __restrict__ out)
{
  __shared__ float  s_s[NCAND];
  __shared__ int    s_c[NCAND];
  __shared__ float  s_q[KDIM];
  __shared__ float  r_s[256];
  __shared__ int    r_c[256];
  __shared__ int    r_p[256];
  __shared__ int    sel_c[32];
  __shared__ double sel_v[32];
  __shared__ int    o_col[TOPK];
  __shared__ int    o_ok[TOPK];

  const int tid = threadIdx.x;
  const int b   = blockIdx.x;

  size_t cbase = (size_t)b * NCAND;
  for (int i = tid; i < NCAND; i += 256) { s_s[i] = cand_s[cbase + i]; s_c[i] = cand_c[cbase + i]; }
  for (int i = tid; i < KDIM; i += 256) s_q[i] = Aq[(size_t)b * KDIM + i];
  if (tid < TOPK) { o_ok[tid] = 0; o_col[tid] = 0; }
  __syncthreads();

  for (int k = 0; k < 32; ++k) {
    float best = -INFINITY; int bc = 0x7FFFFFFF; int bp = 0;
    for (int i = tid; i < NCAND; i += 256) {
      float v = s_s[i]; int cc = s_c[i];
      if (v > best || (v == best && cc < bc)) { best = v; bc = cc; bp = i; }
    }
    r_s[tid] = best; r_c[tid] = bc; r_p[tid] = bp;
    __syncthreads();
    for (int off = 128; off > 0; off >>= 1) {
      if (tid < off) {
        float v = r_s[tid + off]; int cc = r_c[tid + off];
        if (v > r_s[tid] || (v == r_s[tid] && cc < r_c[tid])) {
          r_s[tid] = v; r_c[tid] = cc; r_p[tid] = r_p[tid + off];
        }
      }
      __syncthreads();
    }
    if (tid == 0) { sel_c[k] = r_c[0]; s_s[r_p[0]] = -INFINITY; }
    __syncthreads();
  }

  const int wid = tid >> 6, lane = tid & 63;
  for (int q = 0; q < 8; ++q) {
    int i  = wid * 8 + q;
    int cc = sel_c[i];
    bool ok = (cc >= 0 && cc < CAP);
    double a = 0.0;
    if (ok) {
      const float* brow = &Bb[(size_t)cc * KDIM];
      #pragma unroll 4
      for (int j = 0; j < KDIM / 64; ++j) {
        int kk = j * 64 + lane;
        a += (double)s_q[kk] * (double)brow[kk];
      }
    }
    #pragma unroll
    for (int off = 32; off > 0; off >>= 1) a += __shfl_down(a, off);
    if (lane == 0) sel_v[i] = ok ? a : -INFINITY;
  }
  __syncthreads();

  if (tid < 32) {
    double my = sel_v[tid]; int mc = sel_c[tid];
    int rank = 0;
    for (int j = 0; j < 32; ++j) {
      double ov = sel_v[j]; int oc = sel_c[j];
      if (ov > my || (ov == my && (oc < mc || (oc == mc && j < tid)))) ++rank;
    }
    if (rank < TOPK) {
      double simv = my * (1.0 / 40.0);
      int pass = (my != -INFINITY) && (simv >= 0.3);
      out[(size_t)BQ * TOPK * CDIM + (size_t)b * TOPK + rank] = pass ? (float)simv : 0.0f;
      o_col[rank] = mc; o_ok[rank] = pass;
    }
  }
  __syncthreads();

  for (int idx = tid; idx < TOPK * CDIM; idx += 256) {
    int slot = idx / CDIM;
    int d    = idx - slot * CDIM;
    float v  = 0.f;
    if (o_ok[slot]) v = content[(size_t)o_col[slot] * CDIM + d];
    out[(size_t)b * TOPK * CDIM + idx] = v;
  }
}

extern "C" void kernel_launch(void* const* d_in, const int* in_sizes, int n_in,
                              void* d_out, int out_size, void* d_ws, size_t ws_size,
                              hipStream_t stream) {
  const float* q        = (const float*)d_in[0];
  const float* bank     = (const float*)d_in[1];
  const float* content  = (const float*)d_in[2];
  const int*   valid    = (const int*)d_in[3];
  float* out = (float*)d_out;

  if (ws_size >= WSI_NEED) {
    unsigned char* Bt = (unsigned char*)d_ws + WSI_B;
    unsigned char* At = (unsigned char*)d_ws + WSI_A;
    int* cand_v = (int*)((char*)d_ws + WSI_CV);
    int* cand_c = (int*)((char*)d_ws + WSI_CC);

    k_cvt_i8<<<dim3(4096), dim3(256), 0, stream>>>(bank, Bt, NT * 16384, CAP);
    k_cvt_i8<<<dim3(512),  dim3(256), 0, stream>>>(q,    At, MT * 16384, BQ);
    k_gemm_i8<<<dim3(98 * 64), dim3(256), 0, stream>>>(At, Bt, valid, cand_v, cand_c);
    k_select16<<<dim3(BQ), dim3(256), 0, stream>>>(q, bank, content, cand_v, cand_c, out);
  } else {
    float* cand_s = (float*)d_ws;
    int*   cand_c = (int*)((char*)d_ws + (size_t)BQ * NCAND * 4);
    k_gemm_cand<<<dim3(MT * NT), dim3(256), 0, stream>>>(q, bank, valid, cand_s, cand_c);
    k_select<<<dim3(BQ), dim3(256), 0, stream>>>(q, bank, content, cand_s, cand_c, out);
  }
}